// Round 1
// baseline (372.715 us; speedup 1.0000x reference)
//
#include <hip/hip_runtime.h>
#include <hip/hip_bf16.h>

#define HS 64
#define NH 16
#define NG 16
#define TT 2048
#define CC 1024
#define BBATCH 4
#define TG 128
#define SS 129   // TG+1

typedef __attribute__((ext_vector_type(8))) short bf16x8;
typedef __attribute__((ext_vector_type(4))) float f32x4;

__device__ __forceinline__ float bf2f(ushort u) {
  return __uint_as_float(((unsigned)u) << 16);
}
__device__ __forceinline__ ushort f2bf(float f) {
  unsigned x = __float_as_uint(f);
  x += 0x7fff + ((x >> 16) & 1);
  return (ushort)(x >> 16);
}

// ---------------- fp32 -> bf16 convert ----------------
__global__ void cvt_f32_bf16(const float* __restrict__ src, ushort* __restrict__ dst, int n4) {
  int stride = gridDim.x * blockDim.x;
  for (int i = blockIdx.x * blockDim.x + threadIdx.x; i < n4; i += stride) {
    float4 v = ((const float4*)src)[i];
    ushort4 o;
    o.x = f2bf(v.x); o.y = f2bf(v.y); o.z = f2bf(v.z); o.w = f2bf(v.w);
    ((ushort4*)dst)[i] = o;
  }
}

// ---------------- bf16 GEMM:  C[m][n] = sum_k A[m][k] * Bw[n][k] ----------------
// A: M x K bf16 row-major, Bw: N x K bf16 row-major (i.e. multiply by Bw^T)
template <bool OUT_BF16>
__global__ __launch_bounds__(256) void gemm_bt(const ushort* __restrict__ A,
                                               const ushort* __restrict__ Bw,
                                               void* __restrict__ Cout,
                                               int M, int N, int K) {
  __shared__ ushort As[128][68];
  __shared__ ushort Bs[128][68];
  const int m0 = blockIdx.y * 128;
  const int n0 = blockIdx.x * 128;
  const int tid = threadIdx.x;
  const int lane = tid & 63;
  const int wv = tid >> 6;
  const int wr = wv >> 1, wc = wv & 1;
  const int lo = lane & 15, hi = lane >> 4;

  f32x4 acc[4][4];
#pragma unroll
  for (int i = 0; i < 4; ++i)
#pragma unroll
    for (int j = 0; j < 4; ++j) acc[i][j] = (f32x4)0.0f;

  for (int k0 = 0; k0 < K; k0 += 64) {
    __syncthreads();
#pragma unroll
    for (int t = 0; t < 4; ++t) {
      int c = tid + 256 * t;
      int row = c >> 3, cc = c & 7;
      uint4 va = *(const uint4*)(A + (size_t)(m0 + row) * K + k0 + cc * 8);
      *(uint2*)&As[row][cc * 8]     = make_uint2(va.x, va.y);
      *(uint2*)&As[row][cc * 8 + 4] = make_uint2(va.z, va.w);
      uint4 vb = *(const uint4*)(Bw + (size_t)(n0 + row) * K + k0 + cc * 8);
      *(uint2*)&Bs[row][cc * 8]     = make_uint2(vb.x, vb.y);
      *(uint2*)&Bs[row][cc * 8 + 4] = make_uint2(vb.z, vb.w);
    }
    __syncthreads();
#pragma unroll
    for (int kk = 0; kk < 64; kk += 32) {
      bf16x8 af[4], bfr[4];
#pragma unroll
      for (int i = 0; i < 4; ++i) {
        int r = wr * 64 + i * 16 + lo;
        ushort4 a0 = *(const ushort4*)&As[r][kk + 4 * hi];
        ushort4 a1 = *(const ushort4*)&As[r][kk + 16 + 4 * hi];
        bf16x8 v;
        v[0] = (short)a0.x; v[1] = (short)a0.y; v[2] = (short)a0.z; v[3] = (short)a0.w;
        v[4] = (short)a1.x; v[5] = (short)a1.y; v[6] = (short)a1.z; v[7] = (short)a1.w;
        af[i] = v;
      }
#pragma unroll
      for (int j = 0; j < 4; ++j) {
        int r = wc * 64 + j * 16 + lo;
        ushort4 b0 = *(const ushort4*)&Bs[r][kk + 4 * hi];
        ushort4 b1 = *(const ushort4*)&Bs[r][kk + 16 + 4 * hi];
        bf16x8 v;
        v[0] = (short)b0.x; v[1] = (short)b0.y; v[2] = (short)b0.z; v[3] = (short)b0.w;
        v[4] = (short)b1.x; v[5] = (short)b1.y; v[6] = (short)b1.z; v[7] = (short)b1.w;
        bfr[j] = v;
      }
#pragma unroll
      for (int i = 0; i < 4; ++i)
#pragma unroll
        for (int j = 0; j < 4; ++j)
          acc[i][j] = __builtin_amdgcn_mfma_f32_16x16x32_bf16(af[i], bfr[j], acc[i][j], 0, 0, 0);
    }
  }
  // epilogue: D row = 4*hi + reg, col = lo (within each 16x16 frag)
#pragma unroll
  for (int i = 0; i < 4; ++i) {
    int row = m0 + wr * 64 + i * 16 + 4 * hi;
#pragma unroll
    for (int j = 0; j < 4; ++j) {
      int col = n0 + wc * 64 + j * 16 + lo;
#pragma unroll
      for (int r = 0; r < 4; ++r) {
        float v = acc[i][j][r];
        if constexpr (OUT_BF16) {
          ((ushort*)Cout)[(size_t)(row + r) * N + col] = f2bf(v);
        } else {
          ((float*)Cout)[(size_t)(row + r) * N + col] = v;
        }
      }
    }
  }
}

// ---------------- RoPE + regroup + per-group mean token ----------------
// qkv: (B*T) x 3C bf16.  Writes qg/kg/vg: (B,H,G,129,64) bf16, y_q/y_k fp32.
__global__ __launch_bounds__(256) void rope_group(const ushort* __restrict__ qkv,
                                                  const float* __restrict__ fc,
                                                  const float* __restrict__ fs,
                                                  ushort* __restrict__ qg, ushort* __restrict__ kg,
                                                  ushort* __restrict__ vg,
                                                  float* __restrict__ yq, float* __restrict__ yk) {
  int blk = blockIdx.x;              // ((b*16+h)*16+g)
  int g = blk & 15, h = (blk >> 4) & 15, b = blk >> 8;
  int tid = threadIdx.x;
  int d2 = tid & 31, s0 = tid >> 5;
  size_t gbase = (size_t)blk * SS * HS;
  float sq0 = 0, sq1 = 0, sk0 = 0, sk1 = 0, sv0 = 0, sv1 = 0;
#pragma unroll
  for (int it = 0; it < 16; ++it) {
    int s = s0 + 8 * it;
    int t = g * TG + s;
    size_t rowoff = ((size_t)(b * TT + t)) * (3 * CC) + h * HS + 2 * d2;
    float c = fc[t * 32 + d2], sn = fs[t * 32 + d2];
    ushort2 qu = *(const ushort2*)(qkv + rowoff);
    float qa = bf2f(qu.x), qb = bf2f(qu.y);
    float rq0 = qa * c - qb * sn, rq1 = qa * sn + qb * c;
    ushort2 ku = *(const ushort2*)(qkv + rowoff + CC);
    float ka = bf2f(ku.x), kb = bf2f(ku.y);
    float rk0 = ka * c - kb * sn, rk1 = ka * sn + kb * c;
    ushort2 vu = *(const ushort2*)(qkv + rowoff + 2 * CC);
    float v0 = bf2f(vu.x), v1 = bf2f(vu.y);
    *(ushort2*)(qg + gbase + s * HS + 2 * d2) = make_ushort2(f2bf(rq0), f2bf(rq1));
    *(ushort2*)(kg + gbase + s * HS + 2 * d2) = make_ushort2(f2bf(rk0), f2bf(rk1));
    *(ushort2*)(vg + gbase + s * HS + 2 * d2) = vu;
    sq0 += rq0; sq1 += rq1; sk0 += rk0; sk1 += rk1; sv0 += v0; sv1 += v1;
  }
  __shared__ float red[256][6];
  red[tid][0] = sq0; red[tid][1] = sq1; red[tid][2] = sk0;
  red[tid][3] = sk1; red[tid][4] = sv0; red[tid][5] = sv1;
  __syncthreads();
  if (tid < 32) {
    float m[6];
#pragma unroll
    for (int c = 0; c < 6; ++c) {
      float acc = 0;
#pragma unroll
      for (int r = 0; r < 8; ++r) acc += red[r * 32 + tid][c];
      m[c] = acc * (1.0f / 128.0f);
    }
    *(ushort2*)(qg + gbase + 128 * HS + 2 * tid) = make_ushort2(f2bf(m[0]), f2bf(m[1]));
    *(ushort2*)(kg + gbase + 128 * HS + 2 * tid) = make_ushort2(f2bf(m[2]), f2bf(m[3]));
    *(ushort2*)(vg + gbase + 128 * HS + 2 * tid) = make_ushort2(f2bf(m[4]), f2bf(m[5]));
    if (g < 15) {
      size_t yo = ((size_t)(b * 16 + h) * 15 + g) * 64 + 2 * tid;
      yq[yo] = m[0]; yq[yo + 1] = m[1];
      yk[yo] = m[2]; yk[yo + 1] = m[3];
    }
  }
}

// ---------------- causal attention per (b,h,g), S=129, d=64 ----------------
__global__ __launch_bounds__(256) void attn1(const ushort* __restrict__ qg,
                                             const ushort* __restrict__ kg,
                                             const ushort* __restrict__ vg,
                                             ushort* __restrict__ xo, float* __restrict__ attm) {
  __shared__ ushort qs[SS][68], ks[SS][68], vs[SS][68];
  __shared__ float p_lds[4][132];
  int blk = blockIdx.x;
  int g = blk & 15, h = (blk >> 4) & 15, b = blk >> 8;
  int tid = threadIdx.x;
  size_t gbase = (size_t)blk * SS * HS;
  for (int idx = tid; idx < SS * 16; idx += 256) {
    int s = idx >> 4, c4 = idx & 15;
    *(ushort4*)&qs[s][c4 * 4] = *(const ushort4*)(qg + gbase + s * HS + c4 * 4);
    *(ushort4*)&ks[s][c4 * 4] = *(const ushort4*)(kg + gbase + s * HS + c4 * 4);
    *(ushort4*)&vs[s][c4 * 4] = *(const ushort4*)(vg + gbase + s * HS + c4 * 4);
  }
  __syncthreads();
  int wv = tid >> 6, lane = tid & 63;
  for (int i = wv; i < SS; i += 4) {
    int nk = i + 1;
    int j0 = lane, j1 = lane + 64, j2 = lane + 128;
    int j1c = j1 <= 128 ? j1 : 128;
    int j2c = j2 <= 128 ? j2 : 128;
    float a0 = 0, a1 = 0, a2 = 0;
#pragma unroll
    for (int dc = 0; dc < 16; ++dc) {
      ushort4 q4 = *(const ushort4*)&qs[i][dc * 4];
      float q0 = bf2f(q4.x), q1 = bf2f(q4.y), q2 = bf2f(q4.z), q3 = bf2f(q4.w);
      ushort4 k4 = *(const ushort4*)&ks[j0][dc * 4];
      a0 += q0 * bf2f(k4.x) + q1 * bf2f(k4.y) + q2 * bf2f(k4.z) + q3 * bf2f(k4.w);
      k4 = *(const ushort4*)&ks[j1c][dc * 4];
      a1 += q0 * bf2f(k4.x) + q1 * bf2f(k4.y) + q2 * bf2f(k4.z) + q3 * bf2f(k4.w);
      k4 = *(const ushort4*)&ks[j2c][dc * 4];
      a2 += q0 * bf2f(k4.x) + q1 * bf2f(k4.y) + q2 * bf2f(k4.z) + q3 * bf2f(k4.w);
    }
    float s0v = (j0 < nk) ? a0 * 0.125f : -INFINITY;
    float s1v = (j1 < nk) ? a1 * 0.125f : -INFINITY;
    float s2v = (j2 < nk) ? a2 * 0.125f : -INFINITY;
    float mx = fmaxf(s0v, fmaxf(s1v, s2v));
#pragma unroll
    for (int off = 32; off > 0; off >>= 1) mx = fmaxf(mx, __shfl_xor(mx, off));
    float e0 = __expf(s0v - mx), e1 = __expf(s1v - mx), e2 = __expf(s2v - mx);
    float den = e0 + e1 + e2;
#pragma unroll
    for (int off = 32; off > 0; off >>= 1) den += __shfl_xor(den, off);
    float inv = 1.0f / den;
    p_lds[wv][j0] = e0 * inv;
    p_lds[wv][j1] = e1 * inv;
    if (j2 == 128) p_lds[wv][j2] = e2 * inv;
    asm volatile("s_waitcnt lgkmcnt(0)" ::: "memory");
    float o = 0;
    for (int j = 0; j < nk; ++j) o += p_lds[wv][j] * bf2f(vs[j][lane]);
    if (i < 128) {
      xo[((size_t)(b * TT) + g * TG + i) * CC + h * HS + lane] = f2bf(o);
    } else {
      attm[(size_t)blk * 64 + lane] = o;
    }
  }
}

// ---------------- second (tiny) causal attention over 15 group-mean tokens ----------------
__global__ __launch_bounds__(64) void attn2(const float* __restrict__ yq,
                                            const float* __restrict__ yk,
                                            const float* __restrict__ attm,
                                            float* __restrict__ yv) {
  __shared__ float qs2[15][64], ks2[15][64], avs[15][64], srow[16];
  int bh = blockIdx.x, lane = threadIdx.x;
  for (int j = 0; j < 15; ++j) {
    qs2[j][lane] = yq[((size_t)bh * 15 + j) * 64 + lane];
    ks2[j][lane] = yk[((size_t)bh * 15 + j) * 64 + lane];
    avs[j][lane] = attm[((size_t)bh * 16 + j) * 64 + lane];
  }
  __syncthreads();
  for (int i = 0; i < 15; ++i) {
    float qv = qs2[i][lane];
    for (int j = 0; j <= i; ++j) {
      float t = qv * ks2[j][lane];
#pragma unroll
      for (int off = 32; off > 0; off >>= 1) t += __shfl_xor(t, off);
      if (lane == 0) srow[j] = t * 0.125f;
    }
    __syncthreads();
    float mx = -INFINITY;
    for (int j = 0; j <= i; ++j) mx = fmaxf(mx, srow[j]);
    float den = 0;
    for (int j = 0; j <= i; ++j) den += __expf(srow[j] - mx);
    float inv = 1.0f / den;
    float o = 0;
    for (int j = 0; j <= i; ++j) o += __expf(srow[j] - mx) * inv * avs[j][lane];
    yv[((size_t)bh * 15 + i) * 64 + lane] = o;
    __syncthreads();
  }
}

extern "C" void kernel_launch(void* const* d_in, const int* in_sizes, int n_in,
                              void* d_out, int out_size, void* d_ws, size_t ws_size,
                              hipStream_t stream) {
  const float* x      = (const float*)d_in[0];
  const float* w_attn = (const float*)d_in[1];
  const float* w_proj = (const float*)d_in[2];
  const float* fc     = (const float*)d_in[3];
  const float* fs     = (const float*)d_in[4];
  float* out = (float*)d_out;

  char* ws = (char*)d_ws;
  // layout (bytes):
  ushort* xb   = (ushort*)(ws);               // 16,777,216  (x bf16; dead after qkv gemm)
  ushort* xo   = (ushort*)(ws);               // reuse xb region for xo
  ushort* wab  = (ushort*)(ws + 16777216);    // 6,291,456  (dead after qkv gemm)
  float*  attm = (float*) (ws + 16777216);    // 262,144    reuse wab region
  ushort* wpb  = (ushort*)(ws + 23068672);    // 2,097,152
  ushort* qkv  = (ushort*)(ws + 25165824);    // 50,331,648
  ushort* qg   = (ushort*)(ws + 75497472);    // 16,908,288
  ushort* kg   = (ushort*)(ws + 92405760);    // 16,908,288
  ushort* vg   = (ushort*)(ws + 109314048);   // 16,908,288 -> end 126,222,336

  float* yq = out + 8388608;
  float* yk = out + 8450048;
  float* yv = out + 8511488;

  cvt_f32_bf16<<<2048, 256, 0, stream>>>(x, xb, 8388608 / 4);
  cvt_f32_bf16<<<1024, 256, 0, stream>>>(w_attn, wab, 3145728 / 4);
  cvt_f32_bf16<<<512, 256, 0, stream>>>(w_proj, wpb, 1048576 / 4);
  gemm_bt<true><<<dim3(24, 64), 256, 0, stream>>>(xb, wab, qkv, 8192, 3072, 1024);
  rope_group<<<1024, 256, 0, stream>>>(qkv, fc, fs, qg, kg, vg, yq, yk);
  attn1<<<1024, 256, 0, stream>>>(qg, kg, vg, xo, attm);
  attn2<<<64, 64, 0, stream>>>(yq, yk, attm, yv);
  gemm_bt<false><<<dim3(8, 64), 256, 0, stream>>>(xo, wpb, out, 8192, 1024, 1024);
}

// Round 2
// 199.409 us; speedup vs baseline: 1.8691x; 1.8691x over previous
//
#include <hip/hip_runtime.h>
#include <hip/hip_bf16.h>

#define HS 64
#define NH 16
#define NG 16
#define TT 2048
#define CC 1024
#define BBATCH 4
#define TG 128
#define SS 129   // TG+1

typedef __attribute__((ext_vector_type(8))) short bf16x8;
typedef __attribute__((ext_vector_type(4))) float f32x4;

__device__ __forceinline__ float bf2f(ushort u) {
  return __uint_as_float(((unsigned)u) << 16);
}
__device__ __forceinline__ ushort f2bf(float f) {
  unsigned x = __float_as_uint(f);
  x += 0x7fff + ((x >> 16) & 1);
  return (ushort)(x >> 16);
}
__device__ __forceinline__ bf16x8 mk8(ushort4 a0, ushort4 a1) {
  bf16x8 v;
  v[0] = (short)a0.x; v[1] = (short)a0.y; v[2] = (short)a0.z; v[3] = (short)a0.w;
  v[4] = (short)a1.x; v[5] = (short)a1.y; v[6] = (short)a1.z; v[7] = (short)a1.w;
  return v;
}

// ---------------- fp32 -> bf16 convert ----------------
__global__ void cvt_f32_bf16(const float* __restrict__ src, ushort* __restrict__ dst, int n4) {
  int stride = gridDim.x * blockDim.x;
  for (int i = blockIdx.x * blockDim.x + threadIdx.x; i < n4; i += stride) {
    float4 v = ((const float4*)src)[i];
    ushort4 o;
    o.x = f2bf(v.x); o.y = f2bf(v.y); o.z = f2bf(v.z); o.w = f2bf(v.w);
    ((ushort4*)dst)[i] = o;
  }
}

// ---------------- bf16 GEMM:  C[m][n] = sum_k A[m][k] * Bw[n][k] ----------------
template <bool OUT_BF16>
__global__ __launch_bounds__(256) void gemm_bt(const ushort* __restrict__ A,
                                               const ushort* __restrict__ Bw,
                                               void* __restrict__ Cout,
                                               int M, int N, int K) {
  __shared__ ushort As[128][68];
  __shared__ ushort Bs[128][68];
  const int m0 = blockIdx.y * 128;
  const int n0 = blockIdx.x * 128;
  const int tid = threadIdx.x;
  const int lane = tid & 63;
  const int wv = tid >> 6;
  const int wr = wv >> 1, wc = wv & 1;
  const int lo = lane & 15, hi = lane >> 4;

  f32x4 acc[4][4];
#pragma unroll
  for (int i = 0; i < 4; ++i)
#pragma unroll
    for (int j = 0; j < 4; ++j) acc[i][j] = (f32x4)0.0f;

  for (int k0 = 0; k0 < K; k0 += 64) {
    __syncthreads();
#pragma unroll
    for (int t = 0; t < 4; ++t) {
      int c = tid + 256 * t;
      int row = c >> 3, cc = c & 7;
      uint4 va = *(const uint4*)(A + (size_t)(m0 + row) * K + k0 + cc * 8);
      *(uint2*)&As[row][cc * 8]     = make_uint2(va.x, va.y);
      *(uint2*)&As[row][cc * 8 + 4] = make_uint2(va.z, va.w);
      uint4 vb = *(const uint4*)(Bw + (size_t)(n0 + row) * K + k0 + cc * 8);
      *(uint2*)&Bs[row][cc * 8]     = make_uint2(vb.x, vb.y);
      *(uint2*)&Bs[row][cc * 8 + 4] = make_uint2(vb.z, vb.w);
    }
    __syncthreads();
#pragma unroll
    for (int kk = 0; kk < 64; kk += 32) {
      bf16x8 af[4], bfr[4];
#pragma unroll
      for (int i = 0; i < 4; ++i) {
        int r = wr * 64 + i * 16 + lo;
        af[i] = mk8(*(const ushort4*)&As[r][kk + 4 * hi],
                    *(const ushort4*)&As[r][kk + 16 + 4 * hi]);
      }
#pragma unroll
      for (int j = 0; j < 4; ++j) {
        int r = wc * 64 + j * 16 + lo;
        bfr[j] = mk8(*(const ushort4*)&Bs[r][kk + 4 * hi],
                     *(const ushort4*)&Bs[r][kk + 16 + 4 * hi]);
      }
#pragma unroll
      for (int i = 0; i < 4; ++i)
#pragma unroll
        for (int j = 0; j < 4; ++j)
          acc[i][j] = __builtin_amdgcn_mfma_f32_16x16x32_bf16(af[i], bfr[j], acc[i][j], 0, 0, 0);
    }
  }
#pragma unroll
  for (int i = 0; i < 4; ++i) {
    int row = m0 + wr * 64 + i * 16 + 4 * hi;
#pragma unroll
    for (int j = 0; j < 4; ++j) {
      int col = n0 + wc * 64 + j * 16 + lo;
#pragma unroll
      for (int r = 0; r < 4; ++r) {
        float v = acc[i][j][r];
        if constexpr (OUT_BF16) {
          ((ushort*)Cout)[(size_t)(row + r) * N + col] = f2bf(v);
        } else {
          ((float*)Cout)[(size_t)(row + r) * N + col] = v;
        }
      }
    }
  }
}

// ---------------- RoPE + regroup + per-group mean token ----------------
__global__ __launch_bounds__(256) void rope_group(const ushort* __restrict__ qkv,
                                                  const float* __restrict__ fc,
                                                  const float* __restrict__ fs,
                                                  ushort* __restrict__ qg, ushort* __restrict__ kg,
                                                  ushort* __restrict__ vg,
                                                  float* __restrict__ yq, float* __restrict__ yk) {
  int blk = blockIdx.x;              // ((b*16+h)*16+g)
  int g = blk & 15, h = (blk >> 4) & 15, b = blk >> 8;
  int tid = threadIdx.x;
  int d2 = tid & 31, s0 = tid >> 5;
  size_t gbase = (size_t)blk * SS * HS;
  float sq0 = 0, sq1 = 0, sk0 = 0, sk1 = 0, sv0 = 0, sv1 = 0;
#pragma unroll
  for (int it = 0; it < 16; ++it) {
    int s = s0 + 8 * it;
    int t = g * TG + s;
    size_t rowoff = ((size_t)(b * TT + t)) * (3 * CC) + h * HS + 2 * d2;
    float c = fc[t * 32 + d2], sn = fs[t * 32 + d2];
    ushort2 qu = *(const ushort2*)(qkv + rowoff);
    float qa = bf2f(qu.x), qb = bf2f(qu.y);
    float rq0 = qa * c - qb * sn, rq1 = qa * sn + qb * c;
    ushort2 ku = *(const ushort2*)(qkv + rowoff + CC);
    float ka = bf2f(ku.x), kb = bf2f(ku.y);
    float rk0 = ka * c - kb * sn, rk1 = ka * sn + kb * c;
    ushort2 vu = *(const ushort2*)(qkv + rowoff + 2 * CC);
    float v0 = bf2f(vu.x), v1 = bf2f(vu.y);
    *(ushort2*)(qg + gbase + s * HS + 2 * d2) = make_ushort2(f2bf(rq0), f2bf(rq1));
    *(ushort2*)(kg + gbase + s * HS + 2 * d2) = make_ushort2(f2bf(rk0), f2bf(rk1));
    *(ushort2*)(vg + gbase + s * HS + 2 * d2) = vu;
    sq0 += rq0; sq1 += rq1; sk0 += rk0; sk1 += rk1; sv0 += v0; sv1 += v1;
  }
  __shared__ float red[256][6];
  red[tid][0] = sq0; red[tid][1] = sq1; red[tid][2] = sk0;
  red[tid][3] = sk1; red[tid][4] = sv0; red[tid][5] = sv1;
  __syncthreads();
  if (tid < 32) {
    float m[6];
#pragma unroll
    for (int c = 0; c < 6; ++c) {
      float acc = 0;
#pragma unroll
      for (int r = 0; r < 8; ++r) acc += red[r * 32 + tid][c];
      m[c] = acc * (1.0f / 128.0f);
    }
    *(ushort2*)(qg + gbase + 128 * HS + 2 * tid) = make_ushort2(f2bf(m[0]), f2bf(m[1]));
    *(ushort2*)(kg + gbase + 128 * HS + 2 * tid) = make_ushort2(f2bf(m[2]), f2bf(m[3]));
    *(ushort2*)(vg + gbase + 128 * HS + 2 * tid) = make_ushort2(f2bf(m[4]), f2bf(m[5]));
    if (g < 15) {
      size_t yo = ((size_t)(b * 16 + h) * 15 + g) * 64 + 2 * tid;
      yq[yo] = m[0]; yq[yo + 1] = m[1];
      yk[yo] = m[2]; yk[yo + 1] = m[3];
    }
  }
}

// ---------------- causal attention per (b,h,g), S=129, d=64 — MFMA version ----------------
// Swapped operands: S^T = K·Q^T  (C row = key, col = query), so P^T C-frags feed
// O^T = V^T·P^T directly as B-operand (C reg index == B k index). V staged transposed.
__global__ __launch_bounds__(256) void attn1(const ushort* __restrict__ qg,
                                             const ushort* __restrict__ kg,
                                             const ushort* __restrict__ vg,
                                             ushort* __restrict__ xo, float* __restrict__ attm) {
  __shared__ ushort qs[144][68];
  __shared__ ushort ks[144][68];
  __shared__ ushort vt[64][148];   // V^T: vt[d][key]; stride 74 dwords (≡10 mod 32, conflict-free)
  __shared__ ushort obuf[4][16][68];
  const int blk = blockIdx.x;
  const int g = blk & 15, h = (blk >> 4) & 15, b = blk >> 8;
  const int tid = threadIdx.x;
  const int lane = tid & 63, wv = tid >> 6;
  const int lo = lane & 15, hi = lane >> 4;
  const size_t gbase = (size_t)blk * SS * HS;

  // zero vt fully (pad keys must be exact 0 to avoid 0*NaN in PV)
  {
    ushort* vflat = &vt[0][0];
    for (int idx = tid; idx < 64 * 148 / 4; idx += 256)
      *(ushort4*)(vflat + idx * 4) = make_ushort4(0, 0, 0, 0);
  }
  __syncthreads();
  // stage Q, K (pad rows zeroed) and V transposed
  for (int idx = tid; idx < 144 * 16; idx += 256) {
    int s = idx >> 4, c = (idx & 15) * 4;
    if (s < SS) {
      *(ushort4*)&qs[s][c] = *(const ushort4*)(qg + gbase + s * HS + c);
      *(ushort4*)&ks[s][c] = *(const ushort4*)(kg + gbase + s * HS + c);
      ushort4 v4 = *(const ushort4*)(vg + gbase + s * HS + c);
      vt[c][s] = v4.x; vt[c + 1][s] = v4.y; vt[c + 2][s] = v4.z; vt[c + 3][s] = v4.w;
    } else {
      *(ushort4*)&qs[s][c] = make_ushort4(0, 0, 0, 0);
      *(ushort4*)&ks[s][c] = make_ushort4(0, 0, 0, 0);
    }
  }
  __syncthreads();

  // wave -> query-tile assignment: {8,1},{7,2},{6,3},{5,4,0}
#pragma unroll
  for (int ti = 0; ti < 3; ++ti) {
    const int t = (ti == 0) ? (8 - wv)
                : (ti == 1) ? ((wv == 3) ? 4 : (wv + 1))
                            : ((wv == 3) ? 0 : -1);
    if (t < 0) continue;
    const int q0 = t * 16;

    // Q B-frags for both k-steps of d=64
    bf16x8 bq[2];
#pragma unroll
    for (int k2 = 0; k2 < 2; ++k2)
      bq[k2] = mk8(*(const ushort4*)&qs[q0 + lo][k2 * 32 + 4 * hi],
                   *(const ushort4*)&qs[q0 + lo][k2 * 32 + 16 + 4 * hi]);

    // S^T = K·Q^T over key tiles 0..t
    f32x4 sc[9];
#pragma unroll
    for (int n = 0; n < 9; ++n) sc[n] = (f32x4)0.0f;
#pragma unroll
    for (int n = 0; n < 9; ++n) {
      if (n > t) continue;
#pragma unroll
      for (int k2 = 0; k2 < 2; ++k2) {
        bf16x8 ak = mk8(*(const ushort4*)&ks[n * 16 + lo][k2 * 32 + 4 * hi],
                        *(const ushort4*)&ks[n * 16 + lo][k2 * 32 + 16 + 4 * hi]);
        sc[n] = __builtin_amdgcn_mfma_f32_16x16x32_bf16(ak, bq[k2], sc[n], 0, 0, 0);
      }
    }

    // mask + scale + softmax (query = q0+lo; key = n*16+4*hi+r)
    const int qi = q0 + lo;
    float mx = -INFINITY;
#pragma unroll
    for (int n = 0; n < 9; ++n) {
      if (n > t) continue;
#pragma unroll
      for (int r = 0; r < 4; ++r) {
        int kj = n * 16 + 4 * hi + r;
        float v = (kj <= qi) ? sc[n][r] * 0.125f : -INFINITY;
        sc[n][r] = v;
        mx = fmaxf(mx, v);
      }
    }
    mx = fmaxf(mx, __shfl_xor(mx, 16));
    mx = fmaxf(mx, __shfl_xor(mx, 32));
    float sum = 0.f;
#pragma unroll
    for (int n = 0; n < 9; ++n) {
      if (n > t) continue;
#pragma unroll
      for (int r = 0; r < 4; ++r) {
        float e = __expf(sc[n][r] - mx);
        sc[n][r] = e;
        sum += e;
      }
    }
    sum += __shfl_xor(sum, 16);
    sum += __shfl_xor(sum, 32);
    const float inv = 1.0f / sum;

    // O^T = V^T · P^T
    f32x4 oac[4];
#pragma unroll
    for (int m = 0; m < 4; ++m) oac[m] = (f32x4)0.0f;
#pragma unroll
    for (int s2 = 0; s2 < 5; ++s2) {
      if (s2 > (t >> 1)) continue;
      const int kt1ok = (2 * s2 + 1 <= t);
      bf16x8 pb;
#pragma unroll
      for (int e = 0; e < 4; ++e) pb[e] = (short)f2bf(sc[2 * s2][e] * inv);
      if (kt1ok) {
#pragma unroll
        for (int e = 0; e < 4; ++e) pb[e + 4] = (short)f2bf(sc[2 * s2 + 1][e] * inv);
      } else {
#pragma unroll
        for (int e = 0; e < 4; ++e) pb[e + 4] = 0;
      }
#pragma unroll
      for (int m = 0; m < 4; ++m) {
        ushort4 a0 = *(const ushort4*)&vt[m * 16 + lo][32 * s2 + 4 * hi];
        ushort4 a1 = kt1ok ? *(const ushort4*)&vt[m * 16 + lo][32 * s2 + 16 + 4 * hi]
                           : make_ushort4(0, 0, 0, 0);
        oac[m] = __builtin_amdgcn_mfma_f32_16x16x32_bf16(mk8(a0, a1), pb, oac[m], 0, 0, 0);
      }
    }

    // write out: O^T frag row = d = m*16+4*hi+r, col = query = lo
    if (t < 8) {
#pragma unroll
      for (int m = 0; m < 4; ++m)
#pragma unroll
        for (int r = 0; r < 4; ++r)
          obuf[wv][lo][m * 16 + 4 * hi + r] = f2bf(oac[m][r]);
#pragma unroll
      for (int it = 0; it < 4; ++it) {
        int idx = lane + 64 * it;
        int r = idx >> 4;
        int c4 = (idx & 15) * 4;
        uint2 val = *(const uint2*)&obuf[wv][r][c4];
        int tok = g * TG + t * 16 + r;
        *(uint2*)(xo + ((size_t)(b * TT + tok)) * CC + h * HS + c4) = val;
      }
    } else {
      if (lo == 0) {
#pragma unroll
        for (int m = 0; m < 4; ++m)
#pragma unroll
          for (int r = 0; r < 4; ++r)
            attm[(size_t)blk * 64 + m * 16 + 4 * hi + r] = oac[m][r];
      }
    }
  }
}

// ---------------- second (tiny) causal attention over 15 group-mean tokens ----------------
__global__ __launch_bounds__(64) void attn2(const float* __restrict__ yq,
                                            const float* __restrict__ yk,
                                            const float* __restrict__ attm,
                                            float* __restrict__ yv) {
  __shared__ float qs2[15][64], ks2[15][64], avs[15][64], srow[16];
  int bh = blockIdx.x, lane = threadIdx.x;
  for (int j = 0; j < 15; ++j) {
    qs2[j][lane] = yq[((size_t)bh * 15 + j) * 64 + lane];
    ks2[j][lane] = yk[((size_t)bh * 15 + j) * 64 + lane];
    avs[j][lane] = attm[((size_t)bh * 16 + j) * 64 + lane];
  }
  __syncthreads();
  for (int i = 0; i < 15; ++i) {
    float qv = qs2[i][lane];
    for (int j = 0; j <= i; ++j) {
      float t = qv * ks2[j][lane];
#pragma unroll
      for (int off = 32; off > 0; off >>= 1) t += __shfl_xor(t, off);
      if (lane == 0) srow[j] = t * 0.125f;
    }
    __syncthreads();
    float mx = -INFINITY;
    for (int j = 0; j <= i; ++j) mx = fmaxf(mx, srow[j]);
    float den = 0;
    for (int j = 0; j <= i; ++j) den += __expf(srow[j] - mx);
    float inv = 1.0f / den;
    float o = 0;
    for (int j = 0; j <= i; ++j) o += __expf(srow[j] - mx) * inv * avs[j][lane];
    yv[((size_t)bh * 15 + i) * 64 + lane] = o;
    __syncthreads();
  }
}

extern "C" void kernel_launch(void* const* d_in, const int* in_sizes, int n_in,
                              void* d_out, int out_size, void* d_ws, size_t ws_size,
                              hipStream_t stream) {
  const float* x      = (const float*)d_in[0];
  const float* w_attn = (const float*)d_in[1];
  const float* w_proj = (const float*)d_in[2];
  const float* fc     = (const float*)d_in[3];
  const float* fs     = (const float*)d_in[4];
  float* out = (float*)d_out;

  char* ws = (char*)d_ws;
  ushort* xb   = (ushort*)(ws);               // x bf16; dead after qkv gemm
  ushort* xo   = (ushort*)(ws);               // reuse xb region
  ushort* wab  = (ushort*)(ws + 16777216);    // dead after qkv gemm
  float*  attm = (float*) (ws + 16777216);    // reuse wab region
  ushort* wpb  = (ushort*)(ws + 23068672);
  ushort* qkv  = (ushort*)(ws + 25165824);
  ushort* qg   = (ushort*)(ws + 75497472);
  ushort* kg   = (ushort*)(ws + 92405760);
  ushort* vg   = (ushort*)(ws + 109314048);

  float* yq = out + 8388608;
  float* yk = out + 8450048;
  float* yv = out + 8511488;

  cvt_f32_bf16<<<2048, 256, 0, stream>>>(x, xb, 8388608 / 4);
  cvt_f32_bf16<<<1024, 256, 0, stream>>>(w_attn, wab, 3145728 / 4);
  cvt_f32_bf16<<<512, 256, 0, stream>>>(w_proj, wpb, 1048576 / 4);
  gemm_bt<true><<<dim3(24, 64), 256, 0, stream>>>(xb, wab, qkv, 8192, 3072, 1024);
  rope_group<<<1024, 256, 0, stream>>>(qkv, fc, fs, qg, kg, vg, yq, yk);
  attn1<<<1024, 256, 0, stream>>>(qg, kg, vg, xo, attm);
  attn2<<<64, 64, 0, stream>>>(yq, yk, attm, yv);
  gemm_bt<false><<<dim3(8, 64), 256, 0, stream>>>(xo, wpb, out, 8192, 1024, 1024);
}